// Round 12
// baseline (53.080 us; speedup 1.0000x reference)
//
#include <hip/hip_runtime.h>
#include <hip/hip_bf16.h>

#define N_IN 4096
#define N_OUT 14336
#define TOPK 1228            // int(4096 * 0.3)

typedef float f32x4 __attribute__((ext_vector_type(4)));

// ---------------------------------------------------------------------------
// Kernel A (slimmed): compute the top-k SELECTION BITMASK only — 64 x u64
// (one bit per element of x), written to workspace. No x_masked writeback.
// Same proven 4-pass radix select on abs-bit patterns, ballot-aggregated
// histogram, single-wave shfl suffix-scan, exact lowest-index-first tie
// ranking. Single block, 1024 threads.
// ---------------------------------------------------------------------------
__global__ __launch_bounds__(1024) void topk_sel_kernel(
    const float* __restrict__ x, unsigned long long* __restrict__ selmask) {
  __shared__ unsigned int s_abs[N_IN];                  // 16 KB
  __shared__ unsigned int s_hist[256];
  __shared__ unsigned int s_pk[4];                      // prefix, krem, eqc
  __shared__ unsigned long long s_cmask[N_IN / 64];     // tie path
  __shared__ unsigned int s_cbase[N_IN / 64];

  const int tid = threadIdx.x;
  const int wv = tid >> 6;
  const int lane = tid & 63;

#pragma unroll
  for (int it = 0; it < N_IN / 1024; ++it) {
    const int i = it * 1024 + tid;
    s_abs[i] = __float_as_uint(x[i]) & 0x7fffffffu;
  }
  if (tid == 0) { s_pk[0] = 0u; s_pk[1] = TOPK; }
  __syncthreads();

  // Radix select, MSB byte -> LSB byte.
  for (int pass = 3; pass >= 0; --pass) {
    const unsigned int prefix = s_pk[0];
    const unsigned int krem = s_pk[1];
    if (tid < 256) s_hist[tid] = 0u;
    __syncthreads();

    const int shift = pass * 8;
    const unsigned int maskAbove =
        (pass == 3) ? 0u : (0xFFFFFFFFu << (shift + 8));

    // Ballot-aggregated histogram: one atomic per distinct bucket per wave.
#pragma unroll
    for (int it = 0; it < N_IN / 1024; ++it) {
      const int i = it * 1024 + tid;
      const unsigned int b = s_abs[i];
      const bool active = ((b & maskAbove) == prefix);
      const unsigned int bucket = (b >> shift) & 0xFFu;
      unsigned long long m = __ballot(active);
#pragma unroll
      for (int bit = 0; bit < 8; ++bit) {
        const unsigned long long vote =
            __ballot(active && ((bucket >> bit) & 1u));
        m &= ((bucket >> bit) & 1u) ? vote : ~vote;
      }
      if (active) {
        const int leader = __ffsll((unsigned long long)m) - 1;
        if (lane == leader)
          atomicAdd(&s_hist[bucket], (unsigned int)__popcll(m));
      }
    }
    __syncthreads();

    // Wave 0: 4 bins/lane + shfl suffix-scan; unique winner updates s_pk.
    if (tid < 64) {
      const unsigned int h0 = s_hist[tid * 4 + 0];
      const unsigned int h1 = s_hist[tid * 4 + 1];
      const unsigned int h2 = s_hist[tid * 4 + 2];
      const unsigned int h3 = s_hist[tid * 4 + 3];
      const unsigned int s = h0 + h1 + h2 + h3;
      unsigned int inc = s;
#pragma unroll
      for (int off = 1; off < 64; off <<= 1) {
        const unsigned int v = __shfl_down(inc, off, 64);
        if (tid + off < 64) inc += v;
      }
      const unsigned int U = inc - s;  // sum over lanes > tid
      const unsigned int C3 = U + h3;
      const unsigned int C2 = C3 + h2;
      const unsigned int C1 = C2 + h1;
      const unsigned int C0 = C1 + h0;
      const unsigned int Carr[4] = {C0, C1, C2, C3};
      const unsigned int Sarr[4] = {C1, C2, C3, U};
      const unsigned int hv[4] = {h0, h1, h2, h3};
#pragma unroll
      for (int j = 0; j < 4; ++j) {
        if (Sarr[j] < krem && krem <= Carr[j]) {
          s_pk[0] = prefix | ((unsigned int)(tid * 4 + j) << shift);
          s_pk[1] = krem - Sarr[j];
          s_pk[2] = hv[j];
        }
      }
    }
    __syncthreads();
  }

  const unsigned int t_abs = s_pk[0];  // bits of TOPK-th largest |x|
  const unsigned int need = s_pk[1];   // # of ==t_abs elems to take (>=1)
  const unsigned int eqc = s_pk[2];    // total # of elems ==t_abs

  if (eqc == need) {  // fast path: no tie ranking needed (overwhelming case)
#pragma unroll
    for (int it = 0; it < N_IN / 1024; ++it) {
      const int i = it * 1024 + tid;
      const unsigned long long m = __ballot(s_abs[i] >= t_abs);
      if (lane == 0) selmask[it * 16 + wv] = m;
    }
  } else {  // exact tie ranking, lowest-index-first (jax.lax.top_k stable)
#pragma unroll
    for (int it = 0; it < N_IN / 1024; ++it) {
      const int i = it * 1024 + tid;
      const bool eq = (s_abs[i] == t_abs);
      const unsigned long long m = __ballot(eq);
      if (lane == 0) s_cmask[i >> 6] = m;
    }
    __syncthreads();
    if (tid < 64) {
      const unsigned int cnt = (unsigned int)__popcll(s_cmask[tid]);
      unsigned int inc = cnt;
#pragma unroll
      for (int off = 1; off < 64; off <<= 1) {
        const unsigned int v = __shfl_up(inc, off, 64);
        if (lane >= off) inc += v;
      }
      s_cbase[tid] = inc - cnt;
    }
    __syncthreads();
#pragma unroll
    for (int it = 0; it < N_IN / 1024; ++it) {
      const int i = it * 1024 + tid;
      const unsigned int b = s_abs[i];
      bool sel = (b > t_abs);
      if (b == t_abs) {
        const unsigned long long below =
            s_cmask[i >> 6] & ((1ull << lane) - 1ull);
        sel = (s_cbase[i >> 6] + (unsigned int)__popcll(below)) < need;
      }
      const unsigned long long m = __ballot(sel);
      if (lane == 0) selmask[it * 16 + wv] = m;
    }
  }
}

// ---------------------------------------------------------------------------
// Kernel B: out[o] = dot(x .* mask, W[o,:]) + bias[o], mask applied INLINE.
// Slab-linear cooperative block (R11 structure): each block owns a
// contiguous 128 KB slab (8 rows), strict linear address order, row = it/4,
// x-chunk = it%4. x read directly from the input; selection applied from the
// 512 B bitmask (~6 VALU per float4, hidden under the W stream). No 16 KB
// x_masked round-trip. W loads non-temporal. Grid 1792 = 7 blocks/CU.
// ---------------------------------------------------------------------------
__global__ __launch_bounds__(256) void masked_matvec_kernel(
    const float* __restrict__ x,
    const unsigned long long* __restrict__ selmask,
    const float* __restrict__ W, const float* __restrict__ bias,
    float* __restrict__ out) {
  __shared__ float s_part[4][8];

  const int tid = threadIdx.x;
  const int wave = tid >> 6;
  const int lane = tid & 63;
  const int row0 = blockIdx.x * 8;

  const f32x4* __restrict__ slab4 =
      reinterpret_cast<const f32x4*>(W + (size_t)row0 * N_IN);
  const f32x4* __restrict__ x4 = reinterpret_cast<const f32x4*>(x);

  // x float4 j covers elements e = j*1024 + 4*tid + {0..3}:
  //   chunk = j*16 + (tid>>4), bit base = (tid&15)*4.
  const unsigned int sh = (tid & 15) * 4;
  f32x4 xv[4];
#pragma unroll
  for (int j = 0; j < 4; ++j) {
    f32x4 v = x4[j * 256 + tid];
    const unsigned int bits =
        (unsigned int)(selmask[j * 16 + (tid >> 4)] >> sh) & 0xFu;
    v.x = (bits & 1u) ? v.x : 0.0f;
    v.y = (bits & 2u) ? v.y : 0.0f;
    v.z = (bits & 4u) ? v.z : 0.0f;
    v.w = (bits & 8u) ? v.w : 0.0f;
    xv[j] = v;
  }

  float acc[8];
#pragma unroll
  for (int r = 0; r < 8; ++r) acc[r] = 0.0f;

  // 32 iterations, fully unrolled: linear addresses idx4 = it*256 + tid.
#pragma unroll
  for (int it = 0; it < 32; ++it) {
    const f32x4 w = __builtin_nontemporal_load(&slab4[it * 256 + tid]);
    const f32x4 v = xv[it & 3];
    acc[it >> 2] += w.x * v.x + w.y * v.y + w.z * v.z + w.w * v.w;
  }

  // Wave-level reduction, then cross-wave via LDS.
#pragma unroll
  for (int r = 0; r < 8; ++r) {
#pragma unroll
    for (int off = 32; off >= 1; off >>= 1)
      acc[r] += __shfl_down(acc[r], off, 64);
  }
  if (lane == 0) {
#pragma unroll
    for (int r = 0; r < 8; ++r) s_part[wave][r] = acc[r];
  }
  __syncthreads();

  if (tid < 8) {
    const float sum =
        s_part[0][tid] + s_part[1][tid] + s_part[2][tid] + s_part[3][tid];
    out[row0 + tid] = sum + bias[row0 + tid];
  }
}

extern "C" void kernel_launch(void* const* d_in, const int* in_sizes, int n_in,
                              void* d_out, int out_size, void* d_ws,
                              size_t ws_size, hipStream_t stream) {
  const float* x    = (const float*)d_in[0];   // (1,1,4096) f32
  const float* W    = (const float*)d_in[1];   // (14336,4096) f32
  const float* bias = (const float*)d_in[2];   // (14336,) f32
  float* out = (float*)d_out;                  // (1,1,14336) f32
  unsigned long long* selmask = (unsigned long long*)d_ws;  // 64 x u64

  topk_sel_kernel<<<1, 1024, 0, stream>>>(x, selmask);
  masked_matvec_kernel<<<N_OUT / 8, 256, 0, stream>>>(x, selmask, W, bias,
                                                      out);
}

// Round 13
// 50.992 us; speedup vs baseline: 1.0409x; 1.0409x over previous
//
#include <hip/hip_runtime.h>
#include <hip/hip_bf16.h>

#define N_IN 4096
#define N_OUT 14336
#define TOPK 1228            // int(4096 * 0.3)

typedef float f32x4 __attribute__((ext_vector_type(4)));

// ---------------------------------------------------------------------------
// Kernel A (proven since round 7): threshold = TOPK-th largest |x| via
// 4-pass radix select on the positive-float bit pattern. Single block,
// 1024 threads. Ballot-aggregated histogram + single-wave shfl suffix-scan.
// Writes x_masked (non-topk zeroed) to workspace.
// ---------------------------------------------------------------------------
__global__ __launch_bounds__(1024) void topk_mask_kernel(
    const float* __restrict__ x, float* __restrict__ x_masked) {
  __shared__ unsigned int s_abs[N_IN];                  // 16 KB
  __shared__ unsigned int s_hist[256];
  __shared__ unsigned int s_pk[4];                      // prefix, krem, eqc
  __shared__ unsigned long long s_cmask[N_IN / 64];     // tie path
  __shared__ unsigned int s_cbase[N_IN / 64];

  const int tid = threadIdx.x;
  const int lane = tid & 63;

#pragma unroll
  for (int it = 0; it < N_IN / 1024; ++it) {
    const int i = it * 1024 + tid;
    s_abs[i] = __float_as_uint(x[i]) & 0x7fffffffu;
  }
  if (tid == 0) { s_pk[0] = 0u; s_pk[1] = TOPK; }
  __syncthreads();

  // Radix select, MSB byte -> LSB byte.
  for (int pass = 3; pass >= 0; --pass) {
    const unsigned int prefix = s_pk[0];
    const unsigned int krem = s_pk[1];
    if (tid < 256) s_hist[tid] = 0u;
    __syncthreads();

    const int shift = pass * 8;
    const unsigned int maskAbove =
        (pass == 3) ? 0u : (0xFFFFFFFFu << (shift + 8));

    // Ballot-aggregated histogram: one atomic per distinct bucket per wave.
#pragma unroll
    for (int it = 0; it < N_IN / 1024; ++it) {
      const int i = it * 1024 + tid;
      const unsigned int b = s_abs[i];
      const bool active = ((b & maskAbove) == prefix);
      const unsigned int bucket = (b >> shift) & 0xFFu;
      unsigned long long m = __ballot(active);
#pragma unroll
      for (int bit = 0; bit < 8; ++bit) {
        const unsigned long long vote =
            __ballot(active && ((bucket >> bit) & 1u));
        m &= ((bucket >> bit) & 1u) ? vote : ~vote;
      }
      if (active) {
        const int leader = __ffsll((unsigned long long)m) - 1;
        if (lane == leader)
          atomicAdd(&s_hist[bucket], (unsigned int)__popcll(m));
      }
    }
    __syncthreads();

    // Wave 0: 4 bins/lane + shfl suffix-scan; unique winner updates s_pk.
    if (tid < 64) {
      const unsigned int h0 = s_hist[tid * 4 + 0];
      const unsigned int h1 = s_hist[tid * 4 + 1];
      const unsigned int h2 = s_hist[tid * 4 + 2];
      const unsigned int h3 = s_hist[tid * 4 + 3];
      const unsigned int s = h0 + h1 + h2 + h3;
      unsigned int inc = s;
#pragma unroll
      for (int off = 1; off < 64; off <<= 1) {
        const unsigned int v = __shfl_down(inc, off, 64);
        if (tid + off < 64) inc += v;
      }
      const unsigned int U = inc - s;  // sum over lanes > tid
      const unsigned int C3 = U + h3;
      const unsigned int C2 = C3 + h2;
      const unsigned int C1 = C2 + h1;
      const unsigned int C0 = C1 + h0;
      const unsigned int Carr[4] = {C0, C1, C2, C3};
      const unsigned int Sarr[4] = {C1, C2, C3, U};
      const unsigned int hv[4] = {h0, h1, h2, h3};
#pragma unroll
      for (int j = 0; j < 4; ++j) {
        if (Sarr[j] < krem && krem <= Carr[j]) {
          s_pk[0] = prefix | ((unsigned int)(tid * 4 + j) << shift);
          s_pk[1] = krem - Sarr[j];
          s_pk[2] = hv[j];
        }
      }
    }
    __syncthreads();
  }

  const unsigned int t_abs = s_pk[0];  // bits of TOPK-th largest |x|
  const unsigned int need = s_pk[1];   // # of ==t_abs elems to take (>=1)
  const unsigned int eqc = s_pk[2];    // total # of elems ==t_abs

  if (eqc == need) {  // fast path: no tie ranking needed (overwhelming case)
#pragma unroll
    for (int it = 0; it < N_IN / 1024; ++it) {
      const int i = it * 1024 + tid;
      x_masked[i] = (s_abs[i] >= t_abs) ? x[i] : 0.0f;
    }
  } else {  // exact tie ranking, lowest-index-first (jax.lax.top_k stable)
#pragma unroll
    for (int it = 0; it < N_IN / 1024; ++it) {
      const int i = it * 1024 + tid;
      const bool eq = (s_abs[i] == t_abs);
      const unsigned long long m = __ballot(eq);
      if (lane == 0) s_cmask[i >> 6] = m;
    }
    __syncthreads();
    if (tid < 64) {
      const unsigned int cnt = (unsigned int)__popcll(s_cmask[tid]);
      unsigned int inc = cnt;
#pragma unroll
      for (int off = 1; off < 64; off <<= 1) {
        const unsigned int v = __shfl_up(inc, off, 64);
        if (lane >= off) inc += v;
      }
      s_cbase[tid] = inc - cnt;
    }
    __syncthreads();
#pragma unroll
    for (int it = 0; it < N_IN / 1024; ++it) {
      const int i = it * 1024 + tid;
      const unsigned int b = s_abs[i];
      bool sel = (b > t_abs);
      if (b == t_abs) {
        const unsigned long long below =
            s_cmask[i >> 6] & ((1ull << lane) - 1ull);
        sel = (s_cbase[i >> 6] + (unsigned int)__popcll(below)) < need;
      }
      x_masked[i] = sel ? x[i] : 0.0f;
    }
  }
}

// ---------------------------------------------------------------------------
// Kernel B (round-10 best, 51.0 us total): out[o] = dot(x_masked, W[o,:]) +
// bias[o]. 256 threads = 4 waves; each wave owns TWO consecutive rows; x held
// fully in registers (no LDS, no barrier); phase-staggered column walk
// (proven +2.6 us); W loads NON-TEMPORAL (pure 235 MB stream, zero reuse).
// ---------------------------------------------------------------------------
__global__ __launch_bounds__(256) void masked_matvec_kernel(
    const float* __restrict__ xm, const float* __restrict__ W,
    const float* __restrict__ bias, float* __restrict__ out) {
  const int tid = threadIdx.x;
  const int wave = tid >> 6;
  const int lane = tid & 63;
  const int r0 = blockIdx.x * 8 + wave * 2;  // rows r0, r0+1
  const int phase = (r0 >> 1) & 15;

  const f32x4* __restrict__ w0r4 =
      reinterpret_cast<const f32x4*>(W + (size_t)r0 * N_IN);
  const f32x4* __restrict__ w1r4 =
      reinterpret_cast<const f32x4*>(W + (size_t)(r0 + 1) * N_IN);
  const f32x4* __restrict__ x4 = reinterpret_cast<const f32x4*>(xm);

  // Issue W group 0 (8 nt-loads, both rows) FIRST: HBM busy from t=0.
  f32x4 p0[4], p1[4];
#pragma unroll
  for (int j = 0; j < 4; ++j) {
    const int c = (phase + j) & 15;
    p0[j] = __builtin_nontemporal_load(&w0r4[c * 64 + lane]);
    p1[j] = __builtin_nontemporal_load(&w1r4[c * 64 + lane]);
  }

  // x into registers, pre-rotated: xv[j] = chunk (phase+j)&15. L1/L2-hot.
  f32x4 xv[16];
#pragma unroll
  for (int j = 0; j < 16; ++j) {
    const int c = (phase + j) & 15;
    xv[j] = x4[c * 64 + lane];
  }

  float a0[4], a1[4];
#pragma unroll
  for (int j = 0; j < 4; ++j) {
    a0[j] = p0[j].x * xv[j].x + p0[j].y * xv[j].y + p0[j].z * xv[j].z +
            p0[j].w * xv[j].w;
    a1[j] = p1[j].x * xv[j].x + p1[j].y * xv[j].y + p1[j].z * xv[j].z +
            p1[j].w * xv[j].w;
  }

#pragma unroll
  for (int g = 1; g < 4; ++g) {
#pragma unroll
    for (int j = 0; j < 4; ++j) {
      const int c = (phase + g * 4 + j) & 15;
      const f32x4 u0 = __builtin_nontemporal_load(&w0r4[c * 64 + lane]);
      const f32x4 u1 = __builtin_nontemporal_load(&w1r4[c * 64 + lane]);
      const f32x4 v = xv[g * 4 + j];
      a0[j] += u0.x * v.x + u0.y * v.y + u0.z * v.z + u0.w * v.w;
      a1[j] += u1.x * v.x + u1.y * v.y + u1.z * v.z + u1.w * v.w;
    }
  }
  float acc0 = (a0[0] + a0[1]) + (a0[2] + a0[3]);
  float acc1 = (a1[0] + a1[1]) + (a1[2] + a1[3]);

#pragma unroll
  for (int off = 32; off >= 1; off >>= 1) {
    acc0 += __shfl_down(acc0, off, 64);
    acc1 += __shfl_down(acc1, off, 64);
  }

  if (lane == 0) {
    out[r0] = acc0 + bias[r0];
    out[r0 + 1] = acc1 + bias[r0 + 1];
  }
}

extern "C" void kernel_launch(void* const* d_in, const int* in_sizes, int n_in,
                              void* d_out, int out_size, void* d_ws,
                              size_t ws_size, hipStream_t stream) {
  const float* x    = (const float*)d_in[0];   // (1,1,4096) f32
  const float* W    = (const float*)d_in[1];   // (14336,4096) f32
  const float* bias = (const float*)d_in[2];   // (14336,) f32
  float* out = (float*)d_out;                  // (1,1,14336) f32
  float* xm  = (float*)d_ws;                   // 4096 f32 scratch

  topk_mask_kernel<<<1, 1024, 0, stream>>>(x, xm);
  masked_matvec_kernel<<<N_OUT / 8, 256, 0, stream>>>(xm, W, bias, out);
}